// Round 1
// baseline (2847.045 us; speedup 1.0000x reference)
//
#include <hip/hip_runtime.h>

#define NB 64        // batch B
#define NN 10000     // nodes N
#define ND 66        // feature D
#define NO 64        // output O
#define NM 5         // 2K+1 diffusion matrices
#define NE 160000    // edges per support
#define ROWF (ND * NB)     // 4224 floats per node-row
#define ROWV (ROWF / 4)    // 1056 float4 per node-row
#define NC (NN * ND)       // 660000 transpose columns

// ---------- x0 = transpose(inputs): (64, 660000) -> (660000, 64) ----------
__global__ __launch_bounds__(256) void transpose_kernel(const float* __restrict__ in,
                                                        float* __restrict__ out) {
    __shared__ float tile[64][65];   // +1 pad: stride-65 -> 2-way LDS alias (free)
    const int c0 = blockIdx.x * 64;
    const int t  = threadIdx.x;
    const int cl = t & 63;           // column-local on load, b on store
    const int bl = t >> 6;           // 0..3
    if (c0 + cl < NC) {
#pragma unroll
        for (int i = 0; i < 16; i++) {
            const int b = bl + i * 4;
            tile[b][cl] = in[(size_t)b * NC + c0 + cl];
        }
    }
    __syncthreads();
#pragma unroll
    for (int i = 0; i < 16; i++) {
        const int cc = bl + i * 4;
        const int c  = c0 + cc;
        if (c < NC) out[(size_t)c * 64 + cl] = tile[cl][cc];
    }
}

// ---------- CSR build: histogram -> scan -> scatter (per launch, ws is poisoned) ----------
__global__ void hist_kernel(const int* __restrict__ rows, int* __restrict__ cnt) {
    const int e = blockIdx.x * 256 + threadIdx.x;   // grid is exactly NE/256
    atomicAdd(&cnt[rows[e]], 1);
}

__global__ __launch_bounds__(1024) void scan_kernel(const int* __restrict__ cnt,
                                                    int* __restrict__ rp,
                                                    int* __restrict__ cur) {
    __shared__ int sums[1024];
    const int t    = threadIdx.x;
    const int base = t * 10;         // 1024*10 >= NN
    int vals[10];
    int local = 0;
#pragma unroll
    for (int i = 0; i < 10; i++) {
        const int idx = base + i;
        const int v   = (idx < NN) ? cnt[idx] : 0;
        vals[i] = local;             // exclusive within chunk
        local  += v;
    }
    sums[t] = local;
    __syncthreads();
    for (int off = 1; off < 1024; off <<= 1) {
        const int v = (t >= off) ? sums[t - off] : 0;
        __syncthreads();
        sums[t] += v;
        __syncthreads();
    }
    const int excl = (t == 0) ? 0 : sums[t - 1];
#pragma unroll
    for (int i = 0; i < 10; i++) {
        const int idx = base + i;
        if (idx < NN) {
            const int v = excl + vals[i];
            rp[idx]  = v;
            cur[idx] = v;            // running cursor for scatter
        }
    }
    if (t == 1023) rp[NN] = sums[1023];
}

__global__ void scatter_kernel(const int* __restrict__ rows, const int* __restrict__ cols,
                               const float* __restrict__ vals, int* __restrict__ cur,
                               int* __restrict__ scols, float* __restrict__ svals) {
    const int e = blockIdx.x * 256 + threadIdx.x;
    const int r = rows[e];
    const int p = atomicAdd(&cur[r], 1);
    scols[p] = cols[e];
    svals[p] = vals[e];
}

// ---------- y[n,:] = alpha * sum_{e in row n} v_e * x[c_e,:]  (- z[n,:] if z) ----------
__global__ __launch_bounds__(256) void spmm_kernel(const int* __restrict__ rp,
                                                   const int* __restrict__ scols,
                                                   const float* __restrict__ svals,
                                                   const float* __restrict__ x,
                                                   const float* __restrict__ z,
                                                   float* __restrict__ y, float alpha) {
    const int n = blockIdx.x;
    const int t = threadIdx.x;
    const float4* x4 = (const float4*)x;
    float4 acc[5];
#pragma unroll
    for (int k = 0; k < 5; k++) acc[k] = make_float4(0.f, 0.f, 0.f, 0.f);
    const int e0 = rp[n], e1 = rp[n + 1];
    for (int e = e0; e < e1; e++) {
        const int   c = scols[e];
        const float v = alpha * svals[e];
        const float4* src = x4 + (size_t)c * ROWV;
#pragma unroll
        for (int k = 0; k < 5; k++) {
            const int j = t + 256 * k;
            if (j < ROWV) {
                const float4 xv = src[j];
                acc[k].x = fmaf(v, xv.x, acc[k].x);
                acc[k].y = fmaf(v, xv.y, acc[k].y);
                acc[k].z = fmaf(v, xv.z, acc[k].z);
                acc[k].w = fmaf(v, xv.w, acc[k].w);
            }
        }
    }
    float4* y4 = (float4*)y + (size_t)n * ROWV;
    if (z) {
        const float4* z4 = (const float4*)z + (size_t)n * ROWV;
#pragma unroll
        for (int k = 0; k < 5; k++) {
            const int j = t + 256 * k;
            if (j < ROWV) {
                const float4 zv = z4[j];
                float4 r;
                r.x = acc[k].x - zv.x;
                r.y = acc[k].y - zv.y;
                r.z = acc[k].z - zv.z;
                r.w = acc[k].w - zv.w;
                y4[j] = r;
            }
        }
    } else {
#pragma unroll
        for (int k = 0; k < 5; k++) {
            const int j = t + 256 * k;
            if (j < ROWV) y4[j] = acc[k];
        }
    }
}

// ---------- per-node GEMM-accumulate: out[b, n*64+o] (+)= X_n^T(64x66) @ W_m(66x64) ----------
__global__ __launch_bounds__(256) void gemm_kernel(const float* __restrict__ X,
                                                   const float* __restrict__ W,
                                                   const float* __restrict__ bias,
                                                   float* __restrict__ out, int m, int init) {
    __shared__ float Xs[ROWF];       // [d][b], 16.9 KB
    __shared__ float Ws[ND * NO];    // [d][o], 16.9 KB
    const int n = blockIdx.x;
    const int t = threadIdx.x;
    const float4* xr  = (const float4*)(X + (size_t)n * ROWF);
    float4*       Xs4 = (float4*)Xs;
#pragma unroll
    for (int k = 0; k < 5; k++) {
        const int j = t + 256 * k;
        if (j < ROWV) Xs4[j] = xr[j];
    }
    {
        const int o = t & 63;
        for (int d = t >> 6; d < ND; d += 4) Ws[d * 64 + o] = W[(d * NM + m) * NO + o];
    }
    __syncthreads();
    const int bo = (t & 15) * 4;     // output-o tile base
    const int bb = (t >> 4) * 4;     // batch-b tile base
    float acc[4][4];
#pragma unroll
    for (int i = 0; i < 4; i++)
#pragma unroll
        for (int j = 0; j < 4; j++) acc[i][j] = 0.f;
    for (int d = 0; d < ND; d++) {
        const float4 xv = *(const float4*)&Xs[d * 64 + bb];
        const float4 wv = *(const float4*)&Ws[d * 64 + bo];
        acc[0][0] = fmaf(xv.x, wv.x, acc[0][0]);
        acc[0][1] = fmaf(xv.x, wv.y, acc[0][1]);
        acc[0][2] = fmaf(xv.x, wv.z, acc[0][2]);
        acc[0][3] = fmaf(xv.x, wv.w, acc[0][3]);
        acc[1][0] = fmaf(xv.y, wv.x, acc[1][0]);
        acc[1][1] = fmaf(xv.y, wv.y, acc[1][1]);
        acc[1][2] = fmaf(xv.y, wv.z, acc[1][2]);
        acc[1][3] = fmaf(xv.y, wv.w, acc[1][3]);
        acc[2][0] = fmaf(xv.z, wv.x, acc[2][0]);
        acc[2][1] = fmaf(xv.z, wv.y, acc[2][1]);
        acc[2][2] = fmaf(xv.z, wv.z, acc[2][2]);
        acc[2][3] = fmaf(xv.z, wv.w, acc[2][3]);
        acc[3][0] = fmaf(xv.w, wv.x, acc[3][0]);
        acc[3][1] = fmaf(xv.w, wv.y, acc[3][1]);
        acc[3][2] = fmaf(xv.w, wv.z, acc[3][2]);
        acc[3][3] = fmaf(xv.w, wv.w, acc[3][3]);
    }
#pragma unroll
    for (int i = 0; i < 4; i++) {
        const size_t idx = (size_t)(bb + i) * ((size_t)NN * NO) + (size_t)n * NO + bo;
        float4 r = make_float4(acc[i][0], acc[i][1], acc[i][2], acc[i][3]);
        if (init) {
            const float4 bv = *(const float4*)&bias[bo];
            r.x += bv.x; r.y += bv.y; r.z += bv.z; r.w += bv.w;
        } else {
            const float4 pv = *(const float4*)&out[idx];
            r.x += pv.x; r.y += pv.y; r.z += pv.z; r.w += pv.w;
        }
        *(float4*)&out[idx] = r;
    }
}

extern "C" void kernel_launch(void* const* d_in, const int* in_sizes, int n_in,
                              void* d_out, int out_size, void* d_ws, size_t ws_size,
                              hipStream_t stream) {
    const float* inputs = (const float*)d_in[0];
    // d_in[1] = state, unused by forward
    const float* weight = (const float*)d_in[2];   // (330, 64), row = d*5 + m
    const float* biases = (const float*)d_in[3];
    const float* vals0  = (const float*)d_in[4];
    const float* vals1  = (const float*)d_in[5];
    const int*   rows0  = (const int*)d_in[6];
    const int*   cols0  = (const int*)d_in[7];
    const int*   rows1  = (const int*)d_in[8];
    const int*   cols1  = (const int*)d_in[9];
    float* out = (float*)d_out;

    // workspace layout: 3 big matrices + CSR arrays (~510 MB)
    const size_t SZX = (size_t)NN * ROWF;
    float* x0   = (float*)d_ws;
    float* xa   = x0 + SZX;
    float* xb   = xa + SZX;
    int*   cnt0 = (int*)(xb + SZX);
    int*   cnt1 = cnt0 + NN;
    int*   rp0  = cnt1 + NN;
    int*   rp1  = rp0 + (NN + 1);
    int*   cur0 = rp1 + (NN + 1);
    int*   cur1 = cur0 + NN;
    int*   sc0  = cur1 + NN;
    int*   sc1  = sc0 + NE;
    float* sv0  = (float*)(sc1 + NE);
    float* sv1  = sv0 + NE;

    hipMemsetAsync(cnt0, 0, 2 * NN * sizeof(int), stream);
    transpose_kernel<<<(NC + 63) / 64, 256, 0, stream>>>(inputs, x0);

    hist_kernel<<<NE / 256, 256, 0, stream>>>(rows0, cnt0);
    hist_kernel<<<NE / 256, 256, 0, stream>>>(rows1, cnt1);
    scan_kernel<<<1, 1024, 0, stream>>>(cnt0, rp0, cur0);
    scan_kernel<<<1, 1024, 0, stream>>>(cnt1, rp1, cur1);
    scatter_kernel<<<NE / 256, 256, 0, stream>>>(rows0, cols0, vals0, cur0, sc0, sv0);
    scatter_kernel<<<NE / 256, 256, 0, stream>>>(rows1, cols1, vals1, cur1, sc1, sv1);

    // m=0: init out with bias + x0 contribution
    gemm_kernel<<<NN, 256, 0, stream>>>(x0, weight, biases, out, 0, 1);
    // support 0: x1 = A0 x0 ; x2 = 2 A0 x1 - x0
    spmm_kernel<<<NN, 256, 0, stream>>>(rp0, sc0, sv0, x0, nullptr, xa, 1.f);
    gemm_kernel<<<NN, 256, 0, stream>>>(xa, weight, biases, out, 1, 0);
    spmm_kernel<<<NN, 256, 0, stream>>>(rp0, sc0, sv0, xa, x0, xb, 2.f);
    gemm_kernel<<<NN, 256, 0, stream>>>(xb, weight, biases, out, 2, 0);
    // support 1
    spmm_kernel<<<NN, 256, 0, stream>>>(rp1, sc1, sv1, x0, nullptr, xa, 1.f);
    gemm_kernel<<<NN, 256, 0, stream>>>(xa, weight, biases, out, 3, 0);
    spmm_kernel<<<NN, 256, 0, stream>>>(rp1, sc1, sv1, xa, x0, xb, 2.f);
    gemm_kernel<<<NN, 256, 0, stream>>>(xb, weight, biases, out, 4, 0);
}

// Round 2
// 1517.297 us; speedup vs baseline: 1.8764x; 1.8764x over previous
//
#include <hip/hip_runtime.h>

#define NN 10000
#define NE 160000
#define ROWU 2112          // uints per node row (4224 bf16 = 66*64)
#define OUTSTRIDE 640000   // N*O floats per batch image

typedef unsigned int uint;
typedef unsigned short ushort;
typedef __attribute__((ext_vector_type(8))) short short8;
typedef __attribute__((ext_vector_type(4))) float f32x4;

__device__ __forceinline__ float bflo(uint u) { return __uint_as_float(u << 16); }
__device__ __forceinline__ float bfhi(uint u) { return __uint_as_float(u & 0xffff0000u); }
// RTNE pack of two fp32 -> packed bf16 pair
__device__ __forceinline__ uint packbf(float a, float b) {
    uint ua = __float_as_uint(a); ua += 0x7fffu + ((ua >> 16) & 1u);
    uint ub = __float_as_uint(b); ub += 0x7fffu + ((ub >> 16) & 1u);
    return (ua >> 16) | (ub & 0xffff0000u);
}

// ---------- x0[n][b*66+d] (bf16) = inputs[b][n*66+d] ----------
__global__ __launch_bounds__(256) void transpose_kernel(const float* __restrict__ in,
                                                        uint* __restrict__ x0) {
    const int n = blockIdx.x, t = threadIdx.x;
    const float* src = in + (size_t)n * 66;
    uint* dst = x0 + (size_t)n * ROWU;
#pragma unroll
    for (int j = 0; j < 9; j++) {
        const int ui = 256 * j + t;
        if (ui < ROWU) {
            const int idx = 2 * ui;                 // element index b*66+d (even, so no b-cross)
            const int b = (int)(((long long)idx * 63551) >> 22);   // idx/66
            const int d = idx - 66 * b;
            const float a0 = src[(size_t)b * 660000 + d];
            const float a1 = src[(size_t)b * 660000 + d + 1];
            dst[ui] = packbf(a0, a1);
        }
    }
}

// ---------- CSR build ----------
__global__ void hist_kernel(const int* __restrict__ rows, int* __restrict__ cnt) {
    const int e = blockIdx.x * 256 + threadIdx.x;
    atomicAdd(&cnt[rows[e]], 1);
}

__global__ __launch_bounds__(1024) void scan_kernel(const int* __restrict__ cnt,
                                                    int* __restrict__ rp,
                                                    int* __restrict__ cur) {
    __shared__ int sums[1024];
    const int t = threadIdx.x;
    const int base = t * 10;
    int vals[10];
    int local = 0;
#pragma unroll
    for (int i = 0; i < 10; i++) {
        const int idx = base + i;
        const int v = (idx < NN) ? cnt[idx] : 0;
        vals[i] = local;
        local += v;
    }
    sums[t] = local;
    __syncthreads();
    for (int off = 1; off < 1024; off <<= 1) {
        const int v = (t >= off) ? sums[t - off] : 0;
        __syncthreads();
        sums[t] += v;
        __syncthreads();
    }
    const int excl = (t == 0) ? 0 : sums[t - 1];
#pragma unroll
    for (int i = 0; i < 10; i++) {
        const int idx = base + i;
        if (idx < NN) {
            const int v = excl + vals[i];
            rp[idx] = v;
            cur[idx] = v;
        }
    }
    if (t == 1023) rp[NN] = sums[1023];
}

__global__ void scatter_kernel(const int* __restrict__ rows, const int* __restrict__ cols,
                               const float* __restrict__ vals, int* __restrict__ cur,
                               int* __restrict__ scols, float* __restrict__ svals) {
    const int e = blockIdx.x * 256 + threadIdx.x;
    const int r = rows[e];
    const int p = atomicAdd(&cur[r], 1);
    scols[p] = cols[e];
    svals[p] = vals[e];
}

// ---------- Wt[o][k] (bf16, k = m*66+d in [0,352)) = weight[(d*5+m)*64+o] ----------
__global__ __launch_bounds__(256) void wprep_kernel(const float* __restrict__ weight,
                                                    ushort* __restrict__ Wt) {
    const int t = threadIdx.x;
    const int o = t & 63, rep = t >> 6;
    for (int kk = 0; kk < 88; kk++) {
        const int k = rep * 88 + kk;
        float v = 0.f;
        if (k < 330) {
            const int m = (int)(((long long)k * 63551) >> 22);   // k/66
            const int d = k - 66 * m;
            v = weight[(d * 5 + m) * 64 + o];
        }
        uint uv = __float_as_uint(v);
        uv += 0x7fffu + ((uv >> 16) & 1u);
        Wt[o * 352 + k] = (ushort)(uv >> 16);
    }
}

// ---------- y[n,:] = alpha * sum_e v_e * x[c_e,:]  (- z[n,:] if z), bf16 rows ----------
__global__ __launch_bounds__(256) void spmm_kernel(const int* __restrict__ rp,
                                                   const int* __restrict__ scols,
                                                   const float* __restrict__ svals,
                                                   const uint* __restrict__ x,
                                                   const uint* __restrict__ z,
                                                   uint* __restrict__ y, float alpha) {
    const int n = blockIdx.x, t = threadIdx.x;
    float acc[18];
#pragma unroll
    for (int i = 0; i < 18; i++) acc[i] = 0.f;
    const int e0 = rp[n], e1 = rp[n + 1];
    for (int e = e0; e < e1; e++) {
        const int c = scols[e];
        const float v = alpha * svals[e];
        const uint* src = x + (size_t)c * ROWU;
#pragma unroll
        for (int k = 0; k < 8; k++) {
            const uint u = src[t + 256 * k];
            acc[2 * k]     = fmaf(v, bflo(u), acc[2 * k]);
            acc[2 * k + 1] = fmaf(v, bfhi(u), acc[2 * k + 1]);
        }
        if (t < 64) {   // tail: uints 2048..2111 (wave 0 only)
            const uint u = src[2048 + t];
            acc[16] = fmaf(v, bflo(u), acc[16]);
            acc[17] = fmaf(v, bfhi(u), acc[17]);
        }
    }
    uint* yr = y + (size_t)n * ROWU;
    if (z) {
        const uint* zr = z + (size_t)n * ROWU;
#pragma unroll
        for (int k = 0; k < 8; k++) {
            const uint uz = zr[t + 256 * k];
            yr[t + 256 * k] = packbf(acc[2 * k] - bflo(uz), acc[2 * k + 1] - bfhi(uz));
        }
        if (t < 64) {
            const uint uz = zr[2048 + t];
            yr[2048 + t] = packbf(acc[16] - bflo(uz), acc[17] - bfhi(uz));
        }
    } else {
#pragma unroll
        for (int k = 0; k < 8; k++)
            yr[t + 256 * k] = packbf(acc[2 * k], acc[2 * k + 1]);
        if (t < 64)
            yr[2048 + t] = packbf(acc[16], acc[17]);
    }
}

// ---------- single-pass per-node MFMA GEMM: out[b][n*64+o] = bias[o] + sum_k Wt[o][k] X[k][b] ----------
// LDS Xt[b][k]: 64 rows, stride 360 ushorts (720 B = 45*16 B, odd 16B-stride).
__global__ __launch_bounds__(256) void gemm_kernel(const uint* __restrict__ p0,
                                                   const uint* __restrict__ p1,
                                                   const uint* __restrict__ p2,
                                                   const uint* __restrict__ p3,
                                                   const uint* __restrict__ p4,
                                                   const ushort* __restrict__ Wt,
                                                   const float* __restrict__ bias,
                                                   float* __restrict__ out) {
    __shared__ ushort Xt[64 * 360];
    const int n = blockIdx.x, t = threadIdx.x;

    // stage 5 node-rows ([b][d] layout, 33 uints per (m,b) chunk) into Xt[b][m*66+d]
#pragma unroll
    for (int m = 0; m < 5; m++) {
        const uint* src = (m == 0) ? p0 : (m == 1) ? p1 : (m == 2) ? p2 : (m == 3) ? p3 : p4;
        src += (size_t)n * ROWU;
#pragma unroll
        for (int j = 0; j < 9; j++) {
            const int flat = 256 * j + t;          // < 2112
            if (flat < ROWU) {
                const int b = (int)(((long long)flat * 127101) >> 22);  // flat/33
                const int i = flat - 33 * b;
                *(uint*)&Xt[b * 360 + m * 66 + 2 * i] = src[b * 33 + i];
            }
        }
    }
    if (t < 64) {   // zero pad k in [330,360)
#pragma unroll
        for (int i = 0; i < 15; i++)
            *(uint*)&Xt[t * 360 + 330 + 2 * i] = 0u;
    }
    __syncthreads();

    const int w = t >> 6;        // wave -> o-tile
    const int l = t & 63;
    const int q = l >> 4;        // k-chunk quad
    const int r = l & 15;

    // A-operand (Wt) fragments in registers: A[m=lane&15 -> Wt row 16w+r][k chunk q*8 + s*32]
    short8 afr[11];
#pragma unroll
    for (int s = 0; s < 11; s++)
        afr[s] = *(const short8*)&Wt[(16 * w + r) * 352 + s * 32 + q * 8];

    const float4 bv = *(const float4*)&bias[16 * w + 4 * q];

#pragma unroll
    for (int bt = 0; bt < 4; bt++) {
        f32x4 acc = {0.f, 0.f, 0.f, 0.f};
        const ushort* xrow = &Xt[(16 * bt + r) * 360];
#pragma unroll
        for (int s = 0; s < 11; s++) {
            const short8 bfr = *(const short8*)&xrow[s * 32 + q * 8];
            acc = __builtin_amdgcn_mfma_f32_16x16x32_bf16(afr[s], bfr, acc, 0, 0, 0);
        }
        // D: col = lane&15 -> b, row = q*4+reg -> o (consecutive o => float4 store)
        float4 res;
        res.x = acc[0] + bv.x;
        res.y = acc[1] + bv.y;
        res.z = acc[2] + bv.z;
        res.w = acc[3] + bv.w;
        *(float4*)&out[(size_t)(16 * bt + r) * OUTSTRIDE + (size_t)n * 64 + 16 * w + 4 * q] = res;
    }
}

extern "C" void kernel_launch(void* const* d_in, const int* in_sizes, int n_in,
                              void* d_out, int out_size, void* d_ws, size_t ws_size,
                              hipStream_t stream) {
    const float* inputs = (const float*)d_in[0];
    const float* weight = (const float*)d_in[2];
    const float* biases = (const float*)d_in[3];
    const float* vals0  = (const float*)d_in[4];
    const float* vals1  = (const float*)d_in[5];
    const int*   rows0  = (const int*)d_in[6];
    const int*   cols0  = (const int*)d_in[7];
    const int*   rows1  = (const int*)d_in[8];
    const int*   cols1  = (const int*)d_in[9];
    float* out = (float*)d_out;

    // workspace: 5 bf16 X buffers (422.4 MB) + Wt + CSR (~3 MB)
    const size_t SZX = (size_t)NN * ROWU;           // uints per buffer
    uint* x0  = (uint*)d_ws;
    uint* xa0 = x0 + SZX;
    uint* xb0 = xa0 + SZX;
    uint* xa1 = xb0 + SZX;
    uint* xb1 = xa1 + SZX;
    ushort* Wt = (ushort*)(xb1 + SZX);              // 64*352 ushorts
    int* cnt0 = (int*)(Wt + 64 * 352);
    int* cnt1 = cnt0 + NN;
    int* rp0  = cnt1 + NN;
    int* rp1  = rp0 + (NN + 1);
    int* cur0 = rp1 + (NN + 1);
    int* cur1 = cur0 + NN;
    int* sc0  = cur1 + NN;
    int* sc1  = sc0 + NE;
    float* sv0 = (float*)(sc1 + NE);
    float* sv1 = sv0 + NE;

    hipMemsetAsync(cnt0, 0, 2 * NN * sizeof(int), stream);
    transpose_kernel<<<NN, 256, 0, stream>>>(inputs, x0);

    hist_kernel<<<NE / 256, 256, 0, stream>>>(rows0, cnt0);
    hist_kernel<<<NE / 256, 256, 0, stream>>>(rows1, cnt1);
    scan_kernel<<<1, 1024, 0, stream>>>(cnt0, rp0, cur0);
    scan_kernel<<<1, 1024, 0, stream>>>(cnt1, rp1, cur1);
    scatter_kernel<<<NE / 256, 256, 0, stream>>>(rows0, cols0, vals0, cur0, sc0, sv0);
    scatter_kernel<<<NE / 256, 256, 0, stream>>>(rows1, cols1, vals1, cur1, sc1, sv1);
    wprep_kernel<<<1, 256, 0, stream>>>(weight, Wt);

    // m order matches reference xs list: x0, A0 x0, 2A0 x1 - x0, A1 x0, 2A1 x1 - x0
    spmm_kernel<<<NN, 256, 0, stream>>>(rp0, sc0, sv0, x0, nullptr, xa0, 1.f);
    spmm_kernel<<<NN, 256, 0, stream>>>(rp0, sc0, sv0, xa0, x0, xb0, 2.f);
    spmm_kernel<<<NN, 256, 0, stream>>>(rp1, sc1, sv1, x0, nullptr, xa1, 1.f);
    spmm_kernel<<<NN, 256, 0, stream>>>(rp1, sc1, sv1, xa1, x0, xb1, 2.f);

    gemm_kernel<<<NN, 256, 0, stream>>>(x0, xa0, xb0, xa1, xb1, Wt, biases, out);
}